// Round 1
// baseline (75.284 us; speedup 1.0000x reference)
//
#include <hip/hip_runtime.h>

// PathSampling: per node, score 32 paths (sum of centrality over masked
// prefix), stable top-8, emit selected masked paths + their edge rows.
//
// Shapes: paths [100000,32,8] i32, edge_ids [100000,32,7] i32,
// rand_lens [100000,32] i32, centrality [100000] f32, k_path=8.
// Outputs: paths_sel [100000,8,8] i32, edge_ids_sel [100000,8,7] i32,
// concatenated flat in d_out (int32 storage).

#define N_NODE   100000
#define N_PATH   32
#define L_PATH   8
#define K_PATH   8

__global__ __launch_bounds__(256) void path_sampling_kernel(
    const int*   __restrict__ paths,
    const int*   __restrict__ edge_ids,
    const int*   __restrict__ rand_lens,
    const float* __restrict__ centrality,
    int*         __restrict__ out_paths,   // [N_NODE, K_PATH, L_PATH]
    int*         __restrict__ out_edges)   // [N_NODE, K_PATH, L_PATH-1]
{
    const int t    = threadIdx.x;
    const int path = t & 31;                       // path within node
    const int node = blockIdx.x * 8 + (t >> 5);    // 8 nodes per 256-thr block
    if (node >= N_NODE) return;

    const size_t row = (size_t)node * N_PATH + path;

    // Coalesced 32B load of this path's 8 node ids.
    const int4* p4 = (const int4*)(paths + row * L_PATH);
    int4 pa = p4[0];
    int4 pb = p4[1];
    int  len = rand_lens[row];                     // keep positions j <= len

    int mp[8] = {pa.x, pa.y, pa.z, pa.w, pb.x, pb.y, pb.z, pb.w};

    // Mask + gather. Masked slots contribute exactly 0.0f.
    float c[8];
    #pragma unroll
    for (int j = 0; j < 8; ++j) {
        if (j > len) mp[j] = -1;
        c[j] = (mp[j] < 0) ? 0.0f : centrality[mp[j]];
    }

    // numpy pairwise-tree summation order for bit-exact score match.
    const float score = ((c[0] + c[1]) + (c[2] + c[3]))
                      + ((c[4] + c[5]) + (c[6] + c[7]));

    // Stable descending rank within the 32 paths of this node:
    // rank = #{j : s_j > s_i  or  (s_j == s_i and j < i)}.
    // This is a permutation of 0..31; ranks 0..7 are the top-k slots,
    // matching jax.lax.top_k's lower-index-wins tie-break.
    int rank = 0;
    #pragma unroll
    for (int j = 0; j < 32; ++j) {
        float sj = __shfl(score, j, 32);
        rank += (sj > score) || (sj == score && j < path);
    }

    if (rank < K_PATH) {
        const size_t obase = (size_t)node * K_PATH + rank;

        int4* op = (int4*)(out_paths + obase * L_PATH);
        op[0] = make_int4(mp[0], mp[1], mp[2], mp[3]);
        op[1] = make_int4(mp[4], mp[5], mp[6], mp[7]);

        // Edge row gathered UNMASKED (reference takes edge_ids, not masked).
        const int* esrc = edge_ids + row * (L_PATH - 1);
        int*       edst = out_edges + obase * (L_PATH - 1);
        #pragma unroll
        for (int j = 0; j < L_PATH - 1; ++j) edst[j] = esrc[j];
    }
}

extern "C" void kernel_launch(void* const* d_in, const int* in_sizes, int n_in,
                              void* d_out, int out_size, void* d_ws, size_t ws_size,
                              hipStream_t stream) {
    const int*   paths      = (const int*)  d_in[0];
    const int*   edge_ids   = (const int*)  d_in[1];
    const int*   rand_lens  = (const int*)  d_in[2];
    const float* centrality = (const float*)d_in[3];
    // d_in[4] is k_path (scalar, known == 8)

    int* out_paths = (int*)d_out;
    int* out_edges = out_paths + (size_t)N_NODE * K_PATH * L_PATH;

    const int nodes_per_block = 8;   // 256 threads / 32 paths
    const int grid = (N_NODE + nodes_per_block - 1) / nodes_per_block; // 12500

    path_sampling_kernel<<<grid, 256, 0, stream>>>(
        paths, edge_ids, rand_lens, centrality, out_paths, out_edges);
}